// Round 3
// baseline (280.709 us; speedup 1.0000x reference)
//
#include <hip/hip_runtime.h>

#define T_LEN 256
#define K 16
#define B_TOT 8192
#define RSCALE 3.2734375f
#define L2E    1.44269504f

typedef __attribute__((ext_vector_type(8))) short bf16x8;
typedef __attribute__((ext_vector_type(4))) float f32x4;
typedef __attribute__((ext_vector_type(4))) int   i32x4;

union FRAG { i32x4 i; bf16x8 b; };

// pack two f32 into one dword of bf16 (truncation): (bf16(hi)<<16)|bf16(lo)
__device__ __forceinline__ unsigned pkbf(float hi, float lo) {
    return __builtin_amdgcn_perm(__float_as_uint(hi), __float_as_uint(lo), 0x07060302u);
}

// ---------------- pack kernel: tidx byte + per-(b,t) gold contribution ----------------
__global__ __launch_bounds__(256) void pack_ctrl(
    const int* __restrict__ tags, const int* __restrict__ w2w,
    const int* __restrict__ ic,   const int* __restrict__ ds,
    const float* __restrict__ cw, const float* __restrict__ trans,
    const float* __restrict__ start, const float* __restrict__ em,
    unsigned char* __restrict__ tidxB, float* __restrict__ goldp)
{
    int idx = blockIdx.x * 256 + threadIdx.x;   // b*256 + t
    int b = idx >> 8, t = idx & 255;
    int tag = tags[idx];
    float emg = em[(size_t)idx * 16 + tag];
    unsigned char ti = 0;
    float g;
    if (t == 0) {
        g = cw[tag] * (start[tag] + emg);
    } else {
        int off = b * (T_LEN - 1) + (t - 1);
        int tidx = (w2w[off] == 1) ? 0 : ((ic[off] == 0) ? 1 : ((ds[off] == 0) ? 2 : 3));
        ti = (unsigned char)tidx;
        int tp = tags[idx - 1];
        g = cw[tag] * (trans[tidx * 256 + tp * 16 + tag] + emg);
    }
    tidxB[idx] = ti;
    goldp[idx] = g;
}

// ---------------- gold reduction: one wave per sequence ----------------
__global__ __launch_bounds__(256) void gold_red(
    const float* __restrict__ goldp, float* __restrict__ out)
{
    int b = blockIdx.x * 4 + (threadIdx.x >> 6);
    int l = threadIdx.x & 63;
    const float* p = goldp + (size_t)b * 256;
    float s = (p[l] + p[l + 64]) + (p[l + 128] + p[l + 192]);
#pragma unroll
    for (int m = 1; m < 64; m <<= 1) s += __shfl_xor(s, m, 64);
    if (l == 0) out[b] = s;
}

// ---------------- main MFMA recurrence kernel: 16 sequences per wave ----------------
__global__ __launch_bounds__(64) void crf_fwd(
    const float* __restrict__ em, const float* __restrict__ trans,
    const float* __restrict__ start, const unsigned char* __restrict__ tidxB,
    float* __restrict__ out)
{
    const int lane = threadIdx.x;   // 0..63
    const int s = lane & 15;        // sequence (B/D col) AND "to" row for A
    const int g = lane >> 4;        // k-group
    const int b = blockIdx.x * 16 + s;

    // ---- A fragments: E_c^T with hi/lo split across the two K-halves ----
    // A[m=lane&15=to][k=8g+e]: e<4 -> bf16_hi(exp(trans[c][4g+e][to])), e>=4 -> bf16(residual)
    FRAG A[4];
#pragma unroll
    for (int c = 0; c < 4; ++c) {
        float x[4], xl[4];
#pragma unroll
        for (int e = 0; e < 4; ++e) {
            float v = __expf(trans[c * 256 + (4 * g + e) * 16 + s]);
            x[e] = v;
            xl[e] = v - __uint_as_float(__float_as_uint(v) & 0xFFFF0000u);
        }
        A[c].i = (i32x4){ (int)pkbf(x[1], x[0]),  (int)pkbf(x[3], x[2]),
                          (int)pkbf(xl[1], xl[0]), (int)pkbf(xl[3], xl[2]) };
    }

    const float* emb = em + (size_t)b * 4096 + g * 4;
    const unsigned char* tb = tidxB + (size_t)b * 256;

    // ---- preload em t=0..3 ----
    f32x4 emq[4];
#pragma unroll
    for (int t = 0; t < 4; ++t) emq[t] = *(const f32x4*)(emb + t * 16);

    // ---- init V at t=0: V[4g+e][s] = exp(start + em0) ----
    unsigned vp0, vp1;
    {
        f32x4 st4 = *(const f32x4*)(start + 4 * g);
        float v0 = __expf(st4[0] + emq[0][0]);
        float v1 = __expf(st4[1] + emq[0][1]);
        float v2 = __expf(st4[2] + emq[0][2]);
        float v3 = __expf(st4[3] + emq[0][3]);
        vp0 = pkbf(v1, v0); vp1 = pkbf(v3, v2);
    }

    f32x4 exq[2];
    {   // exp factor for t=1
        f32x4 e1 = emq[1], r;
#pragma unroll
        for (int i = 0; i < 4; ++i) r[i] = __builtin_exp2f(fmaf(e1[i], L2E, -RSCALE * L2E));
        exq[1] = r;
    }

    float logC = 0.0f;
    uint4 tq  = *(const uint4*)(tb);
    uint4 tqn = *(const uint4*)(tb + 16);

    auto STEP = [&](int t, int k) __attribute__((always_inline)) {
        unsigned dw = (k < 4) ? tq.x : (k < 8) ? tq.y : (k < 12) ? tq.z : tq.w;
        int ti = (int)((dw >> ((k & 3) * 8)) & 0xFFu);

        int p0 = (int)vp0, p1 = (int)vp1;
        int m00 = (ti == 0) ? p0 : 0, m01 = (ti == 0) ? p1 : 0;
        int m10 = (ti == 1) ? p0 : 0, m11 = (ti == 1) ? p1 : 0;
        int m20 = (ti == 2) ? p0 : 0, m21 = (ti == 2) ? p1 : 0;
        int m30 = (ti == 3) ? p0 : 0, m31 = (ti == 3) ? p1 : 0;
        FRAG B0, B1, B2, B3;
        B0.i = (i32x4){m00, m01, m00, m01};
        B1.i = (i32x4){m10, m11, m10, m11};
        B2.i = (i32x4){m20, m21, m20, m21};
        B3.i = (i32x4){m30, m31, m30, m31};

        f32x4 za = __builtin_amdgcn_mfma_f32_16x16x32_bf16(A[0].b, B0.b, (f32x4)(0.0f), 0, 0, 0);
        za       = __builtin_amdgcn_mfma_f32_16x16x32_bf16(A[1].b, B1.b, za,            0, 0, 0);
        f32x4 zb = __builtin_amdgcn_mfma_f32_16x16x32_bf16(A[2].b, B2.b, (f32x4)(0.0f), 0, 0, 0);
        zb       = __builtin_amdgcn_mfma_f32_16x16x32_bf16(A[3].b, B3.b, zb,            0, 0, 0);

        f32x4 d = (za + zb) * exq[k & 1];

        // prefetch em(t+4) into slot k&3 (slot already consumed)
        int tt = t + 4; if (tt > 255) tt = 255;
        emq[k & 3] = *(const f32x4*)(emb + (size_t)tt * 16);

        // exp factors for t+1 (off critical path)
        {
            f32x4 en = emq[(k + 1) & 3], r;
#pragma unroll
            for (int i = 0; i < 4; ++i) r[i] = __builtin_exp2f(fmaf(en[i], L2E, -RSCALE * L2E));
            exq[(k + 1) & 1] = r;
        }

        if (k == 15) {  // exact power-of-2 renorm once per 16 steps
            float mx = fmaxf(fmaxf(d[0], d[1]), fmaxf(d[2], d[3]));
            mx = fmaxf(mx, __shfl_xor(mx, 16, 64));
            mx = fmaxf(mx, __shfl_xor(mx, 32, 64));
            int e2; (void)frexpf(mx, &e2);
            d[0] = ldexpf(d[0], -e2); d[1] = ldexpf(d[1], -e2);
            d[2] = ldexpf(d[2], -e2); d[3] = ldexpf(d[3], -e2);
            logC += (float)e2 * 0.69314718f;
        }

        vp0 = pkbf(d[1], d[0]);
        vp1 = pkbf(d[3], d[2]);
    };

    // block 0: t = 1..15
#pragma unroll
    for (int k = 1; k < 16; ++k) STEP(k, k);
    // blocks 1..15
    for (int blk = 1; blk < 16; ++blk) {
        tq = tqn;
        int nb = (blk + 1 < 16) ? blk + 1 : 15;
        tqn = *(const uint4*)(tb + nb * 16);
#pragma unroll
        for (int k = 0; k < 16; ++k) STEP(blk * 16 + k, k);
    }

    // ---- final: log_Z = log(sum_j V[j][s]) + 255*R + logC ----
    float f0 = __uint_as_float(vp0 << 16);
    float f1 = __uint_as_float(vp0 & 0xFFFF0000u);
    float f2 = __uint_as_float(vp1 << 16);
    float f3 = __uint_as_float(vp1 & 0xFFFF0000u);
    float su = (f0 + f1) + (f2 + f3);
    su += __shfl_xor(su, 16, 64);
    su += __shfl_xor(su, 32, 64);
    if (g == 0) out[B_TOT + b] = logf(su) + 255.0f * RSCALE + logC;
}

extern "C" void kernel_launch(void* const* d_in, const int* in_sizes, int n_in,
                              void* d_out, int out_size, void* d_ws, size_t ws_size,
                              hipStream_t stream) {
    const float* emissions     = (const float*)d_in[0];
    const int*   tags          = (const int*)  d_in[1];
    const int*   who2who       = (const int*)  d_in[2];
    const int*   init_count    = (const int*)  d_in[3];
    const int*   distance      = (const int*)  d_in[4];
    const float* class_weights = (const float*)d_in[5];
    const float* trans_stack   = (const float*)d_in[6];
    const float* start_scores  = (const float*)d_in[7];
    float* out = (float*)d_out;

    unsigned char* tidxB = (unsigned char*)d_ws;                      // 2 MB
    float*         goldp = (float*)((char*)d_ws + B_TOT * T_LEN);     // 8 MB

    hipLaunchKernelGGL(pack_ctrl, dim3(B_TOT), dim3(256), 0, stream,
                       tags, who2who, init_count, distance,
                       class_weights, trans_stack, start_scores, emissions,
                       tidxB, goldp);

    hipLaunchKernelGGL(crf_fwd, dim3(B_TOT / 16), dim3(64), 0, stream,
                       emissions, trans_stack, start_scores, tidxB, out);

    hipLaunchKernelGGL(gold_red, dim3(B_TOT / 4), dim3(256), 0, stream,
                       goldp, out);
}